// Round 1
// baseline (285.397 us; speedup 1.0000x reference)
//
#include <hip/hip_runtime.h>

#define PEPS 1e-5f

// One block per s x s patch. Each thread caches its slice of the patch in
// registers (VPT float4s), so the pass does exactly one global read and one
// global write per element. BLOCK threads, wave=64.
template<int BLOCK, int S, int P>
__global__ __launch_bounds__(BLOCK) void patch_pass(const float* __restrict__ in,
                                                    float* __restrict__ out)
{
    constexpr int W     = 256;          // image width (and height)
    constexpr int RV    = S / 4;        // float4s per patch row
    constexpr int NVEC  = (S * S) / 4;  // float4s per patch
    constexpr int VPT   = NVEC / BLOCK; // float4s per thread
    constexpr int NWAVE = BLOCK / 64;
    static_assert(VPT * BLOCK == NVEC, "block must evenly cover patch");

    const int tid = threadIdx.x;
    const int pid = blockIdx.x;
    const int img = pid / (P * P);
    const int rem = pid - img * (P * P);
    const int pr  = rem / P;
    const int pc  = rem - pr * P;
    const int base = img * (W * W) + pr * (S * W) + pc * S;

    // ---- load + accumulate sum / sumsq -------------------------------------
    float4 vals[VPT];
    float sum = 0.f, ssq = 0.f;
#pragma unroll
    for (int u = 0; u < VPT; ++u) {
        const int j  = u * BLOCK + tid;     // float4 index within patch
        const int r  = j / RV;              // patch row   (RV is pow2 -> shift)
        const int c4 = j - r * RV;          // float4 col
        const float4 v = *reinterpret_cast<const float4*>(in + base + r * W + c4 * 4);
        vals[u] = v;
        sum += (v.x + v.y) + (v.z + v.w);
        ssq += (v.x * v.x + v.y * v.y) + (v.z * v.z + v.w * v.w);
    }

    // ---- block reduction: wave butterfly -> LDS -> thread 0 ----------------
#pragma unroll
    for (int off = 32; off > 0; off >>= 1) {
        sum += __shfl_xor(sum, off);
        ssq += __shfl_xor(ssq, off);
    }
    __shared__ float red[NWAVE][2];
    __shared__ float stats[2];
    const int wave = tid >> 6;
    if ((tid & 63) == 0) { red[wave][0] = sum; red[wave][1] = ssq; }
    __syncthreads();
    if (tid == 0) {
        float s_ = 0.f, q_ = 0.f;
#pragma unroll
        for (int w = 0; w < NWAVE; ++w) { s_ += red[w][0]; q_ += red[w][1]; }
        constexpr float inv_n = 1.0f / (float)(S * S);
        const float m   = s_ * inv_n;
        const float var = q_ * inv_n - m * m;   // biased var, as in reference
        stats[0] = m;
        stats[1] = rsqrtf(var + PEPS);
    }
    __syncthreads();
    const float m  = stats[0];
    const float rs = stats[1];

    // ---- apply: out = v * (0.5 + 0.5 * sigmoid((v-m)*rstd)) ----------------
#pragma unroll
    for (int u = 0; u < VPT; ++u) {
        const int j  = u * BLOCK + tid;
        const int r  = j / RV;
        const int c4 = j - r * RV;
        const float4 v = vals[u];
        float4 o;
        o.x = v.x * (0.5f + 0.5f / (1.0f + __expf((m - v.x) * rs)));
        o.y = v.y * (0.5f + 0.5f / (1.0f + __expf((m - v.y) * rs)));
        o.z = v.z * (0.5f + 0.5f / (1.0f + __expf((m - v.z) * rs)));
        o.w = v.w * (0.5f + 0.5f / (1.0f + __expf((m - v.w) * rs)));
        *reinterpret_cast<float4*>(out + base + r * W + c4 * 4) = o;
    }
}

extern "C" void kernel_launch(void* const* d_in, const int* in_sizes, int n_in,
                              void* d_out, int out_size, void* d_ws, size_t ws_size,
                              hipStream_t stream)
{
    const float* x = (const float*)d_in[0];
    float* out = (float*)d_out;
    constexpr int IMGS = 16 * 64;   // b * c images of 256x256

    // Reference scales: p=(2,1,0) -> s = 64, 128, 256.
    // Pass 1: x -> out.  Passes 2,3: in-place on out (register-cached, safe).
    patch_pass<256, 64, 4><<<IMGS * 16, 256, 0, stream>>>(x, out);
    patch_pass<256, 128, 2><<<IMGS * 4, 256, 0, stream>>>(out, out);
    patch_pass<1024, 256, 1><<<IMGS, 1024, 0, stream>>>(out, out);
}

// Round 2
// 127.029 us; speedup vs baseline: 2.2467x; 2.2467x over previous
//
#include <hip/hip_runtime.h>

#define PEPS 1e-5f

__device__ __forceinline__ float fast_rcp(float x) { return __builtin_amdgcn_rcpf(x); }

// out_elem = x * (0.5 + 0.5 * sigmoid((x - m) * rs))
__device__ __forceinline__ float patch_one(float x, float m, float rs) {
    const float e = __expf((m - x) * rs);            // exp(-z)
    return x * fmaf(0.5f, fast_rcp(1.0f + e), 0.5f);
}

__device__ __forceinline__ void wave_reduce2(float& a, float& b) {
#pragma unroll
    for (int off = 32; off; off >>= 1) {
        a += __shfl_xor(a, off);
        b += __shfl_xor(b, off);
    }
}

// One block per 256x256 image; one wave per 64x64 patch. All three scales
// (s=64,128,256) applied with data register-resident: 1 global read + 1 write.
__global__ __launch_bounds__(1024) void fused_pyramid(const float* __restrict__ in,
                                                      float* __restrict__ out)
{
    constexpr int W = 256;
    const int tid  = threadIdx.x;
    const int wave = tid >> 6;          // 0..15 -> 4x4 grid of 64x64 patches
    const int lane = tid & 63;
    const int pr   = wave >> 2;
    const int pc   = wave & 3;
    const size_t base = (size_t)blockIdx.x * (W * W) + (size_t)(pr * 64) * W + pc * 64;

    __shared__ float redS[16], redQ[16];

    // ---- load (64 floats/lane) + pass-1 partial sums -----------------------
    float4 v[16];
    float s = 0.f, q = 0.f;
#pragma unroll
    for (int u = 0; u < 16; ++u) {
        const int j  = u * 64 + lane;   // float4 index within patch
        const int r  = j >> 4;          // patch row (16 float4 per 64-wide row)
        const int c4 = j & 15;
        const float4 t = *reinterpret_cast<const float4*>(in + base + (size_t)r * W + c4 * 4);
        v[u] = t;
        s += (t.x + t.y) + (t.z + t.w);
        q = fmaf(t.x, t.x, fmaf(t.y, t.y, fmaf(t.z, t.z, fmaf(t.w, t.w, q))));
    }

    // ---- pass 1 (s=64): stats are wave-local (4096 elems) ------------------
    wave_reduce2(s, q);
    float m  = s * (1.0f / 4096.0f);
    float rs = rsqrtf(fmaf(-m, m, q * (1.0f / 4096.0f)) + PEPS);

    float s2 = 0.f, q2 = 0.f;
#pragma unroll
    for (int u = 0; u < 16; ++u) {
        float4 t = v[u];
        t.x = patch_one(t.x, m, rs);
        t.y = patch_one(t.y, m, rs);
        t.z = patch_one(t.z, m, rs);
        t.w = patch_one(t.w, m, rs);
        v[u] = t;
        s2 += (t.x + t.y) + (t.z + t.w);
        q2 = fmaf(t.x, t.x, fmaf(t.y, t.y, fmaf(t.z, t.z, fmaf(t.w, t.w, q2))));
    }

    // ---- pass 2 (s=128): combine 2x2 waves via LDS -------------------------
    wave_reduce2(s2, q2);
    if (lane == 0) { redS[wave] = s2; redQ[wave] = q2; }
    __syncthreads();
    const int w00 = wave & ~5;          // clears pc bit0 (1) and pr bit0 (4)
    {
        const float S = (redS[w00] + redS[w00 + 1]) + (redS[w00 + 4] + redS[w00 + 5]);
        const float Q = (redQ[w00] + redQ[w00 + 1]) + (redQ[w00 + 4] + redQ[w00 + 5]);
        m  = S * (1.0f / 16384.0f);
        rs = rsqrtf(fmaf(-m, m, Q * (1.0f / 16384.0f)) + PEPS);
    }

    float s3 = 0.f, q3 = 0.f;
#pragma unroll
    for (int u = 0; u < 16; ++u) {
        float4 t = v[u];
        t.x = patch_one(t.x, m, rs);
        t.y = patch_one(t.y, m, rs);
        t.z = patch_one(t.z, m, rs);
        t.w = patch_one(t.w, m, rs);
        v[u] = t;
        s3 += (t.x + t.y) + (t.z + t.w);
        q3 = fmaf(t.x, t.x, fmaf(t.y, t.y, fmaf(t.z, t.z, fmaf(t.w, t.w, q3))));
    }

    // ---- pass 3 (s=256): combine all 16 waves ------------------------------
    wave_reduce2(s3, q3);
    __syncthreads();                    // everyone done reading pass-2 partials
    if (lane == 0) { redS[wave] = s3; redQ[wave] = q3; }
    __syncthreads();
    {
        float S = 0.f, Q = 0.f;
#pragma unroll
        for (int w = 0; w < 16; ++w) { S += redS[w]; Q += redQ[w]; }
        m  = S * (1.0f / 65536.0f);
        rs = rsqrtf(fmaf(-m, m, Q * (1.0f / 65536.0f)) + PEPS);
    }

    // ---- apply pass 3 + store ---------------------------------------------
#pragma unroll
    for (int u = 0; u < 16; ++u) {
        const int j  = u * 64 + lane;
        const int r  = j >> 4;
        const int c4 = j & 15;
        float4 t = v[u];
        t.x = patch_one(t.x, m, rs);
        t.y = patch_one(t.y, m, rs);
        t.z = patch_one(t.z, m, rs);
        t.w = patch_one(t.w, m, rs);
        *reinterpret_cast<float4*>(out + base + (size_t)r * W + c4 * 4) = t;
    }
}

extern "C" void kernel_launch(void* const* d_in, const int* in_sizes, int n_in,
                              void* d_out, int out_size, void* d_ws, size_t ws_size,
                              hipStream_t stream)
{
    const float* x = (const float*)d_in[0];
    float* out = (float*)d_out;
    constexpr int IMGS = 16 * 64;       // b * c images of 256x256
    fused_pyramid<<<IMGS, 1024, 0, stream>>>(x, out);
}